// Round 1
// baseline (1295.418 us; speedup 1.0000x reference)
//
#include <hip/hip_runtime.h>
#include <hip/hip_bf16.h>

#define H 512
#define W 512
#define C 128
#define HO 502
#define WO 502

#define TH 4      // output rows per block
#define TW 16     // output cols per block
#define QR 12     // TH+8 q rows
#define QC 24     // TW+8 real q cols
#define QCP 32    // padded col count (addressing only; cols 24..31 uninit, masked)
#define KC 64     // k chunk staged in LDS
#define KP 72     // padded c stride (word stride 36 ≡ 4 mod 32 -> conflict-free)

typedef __bf16 bf16x8 __attribute__((ext_vector_type(8)));
typedef __bf16 bf16x4 __attribute__((ext_vector_type(4)));
typedef float f32x4 __attribute__((ext_vector_type(4)));

__global__ __launch_bounds__(512, 4)
void corr_kernel(const float* __restrict__ p, const float* __restrict__ q,
                 float* __restrict__ out) {
  __shared__ __bf16 Qs[QR * QCP * KP];  // 27648 elem = 55296 B
  __shared__ __bf16 Ps[TH * TW * KP];   // 4608 elem  =  9216 B

  const int t = threadIdx.x;
  const int wave = t >> 6;
  const int lane = t & 63;
  const int quad = lane >> 4;
  const int l16 = lane & 15;
  const int hl = wave >> 1;    // 0..3 : local output row
  const int ntile = wave & 1;  // 0..1 : j-tile

  const int w0 = blockIdx.x * TW;
  const int h0 = blockIdx.y * TH;
  const int b = blockIdx.z;

  f32x4 acc[9];
#pragma unroll
  for (int dy = 0; dy < 9; ++dy) acc[dy] = (f32x4){0.f, 0.f, 0.f, 0.f};

  for (int kc = 0; kc < C; kc += KC) {
    // ---- stage Q: 12 rows x 24 cols x 64 c (fp32 -> bf16) ----
#pragma unroll
    for (int pass = 0; pass < 9; ++pass) {
      int idx = pass * 512 + t;
      int c4 = (idx & 15) * 4;
      int pair = idx >> 4;          // 0..287
      int row = pair / 24;
      int col = pair - row * 24;
      int gy = min(h0 + 2 + row, H - 1);
      int gx = min(w0 + 2 + col, W - 1);
      const float4 v =
          *(const float4*)&q[(((size_t)b * H + gy) * W + gx) * C + kc + c4];
      bf16x4 bv = {(__bf16)v.x, (__bf16)v.y, (__bf16)v.z, (__bf16)v.w};
      *(bf16x4*)&Qs[(row * QCP + col) * KP + c4] = bv;
    }
    // ---- stage P: 64 px x 64 c ----
#pragma unroll
    for (int pass = 0; pass < 2; ++pass) {
      int idx = pass * 512 + t;
      int c4 = (idx & 15) * 4;
      int px = idx >> 4;  // 0..63 = hl*16 + wl
      int gy = min(h0 + (px >> 4), HO - 1);
      int gx = min(w0 + (px & 15), WO - 1);
      const float4 v =
          *(const float4*)&p[(((size_t)b * HO + gy) * WO + gx) * C + kc + c4];
      bf16x4 bv = {(__bf16)v.x, (__bf16)v.y, (__bf16)v.z, (__bf16)v.w};
      *(bf16x4*)&Ps[px * KP + c4] = bv;
    }
    __syncthreads();

    // ---- compute: per wave, fixed (hl, ntile); loop dy, 2 k-steps ----
#pragma unroll
    for (int ks = 0; ks < KC; ks += 32) {
      bf16x8 a = *(const bf16x8*)&Ps[(hl * TW + l16) * KP + ks + quad * 8];
#pragma unroll
      for (int dy = 0; dy < 9; ++dy) {
        bf16x8 bb = *(const bf16x8*)&Qs[((hl + dy) * QCP + ntile * 16 + l16) * KP +
                                        ks + quad * 8];
        acc[dy] = __builtin_amdgcn_mfma_f32_16x16x32_bf16(a, bb, acc[dy], 0, 0, 0);
      }
    }
    __syncthreads();
  }

  // ---- epilogue: D[m=quad*4+r][n=ntile*16+l16]; dx = n - m, keep 0..8 ----
  const int n = ntile * 16 + l16;
#pragma unroll
  for (int dy = 0; dy < 9; ++dy) {
#pragma unroll
    for (int r = 0; r < 4; ++r) {
      int wl = quad * 4 + r;
      int dx = n - wl;
      int h = h0 + hl, w = w0 + wl;
      if (dx >= 0 && dx < 9 && h < HO && w < WO) {
        out[(((size_t)b * HO + h) * WO + w) * 81 + dy * 9 + dx] = acc[dy][r];
      }
    }
  }
}

extern "C" void kernel_launch(void* const* d_in, const int* in_sizes, int n_in,
                              void* d_out, int out_size, void* d_ws,
                              size_t ws_size, hipStream_t stream) {
  const float* p = (const float*)d_in[0];
  const float* q = (const float*)d_in[1];
  float* out = (float*)d_out;
  dim3 grid((WO + TW - 1) / TW, (HO + TH - 1) / TH, 4);
  corr_kernel<<<grid, dim3(512), 0, stream>>>(p, q, out);
}